// Round 8
// baseline (339.718 us; speedup 1.0000x reference)
//
#include <hip/hip_runtime.h>
#include <cstdint>
#include <cstddef>

typedef unsigned short u16;
typedef unsigned int   u32;

#define E_DIM 768
#define NH    12
#define HD    64
#define SEQ   2048
#define NBATCH 4
#define NBH   48          // NBATCH*NH
#define MTOT  8192        // NBATCH*SEQ
#define NQKV  2304

typedef __bf16 bf16x8 __attribute__((ext_vector_type(8)));
typedef float  f32x4  __attribute__((ext_vector_type(4)));

__device__ __forceinline__ u16 f2b(float f) {
  u32 u = __builtin_bit_cast(u32, f);
  u32 r = (u + 0x7fffu + ((u >> 16) & 1u)) >> 16;   // RNE, finite inputs only
  return (u16)r;
}
__device__ __forceinline__ u32 pk2(float a, float b) {
  return (u32)f2b(a) | ((u32)f2b(b) << 16);
}
__device__ __forceinline__ f32x4 mfma16(bf16x8 a, bf16x8 b, f32x4 c) {
  return __builtin_amdgcn_mfma_f32_16x16x32_bf16(a, b, c, 0, 0, 0);
}
__device__ __forceinline__ void gload_lds16(const void* g, void* l) {
  __builtin_amdgcn_global_load_lds((const __attribute__((address_space(1))) void*)g,
                                   (__attribute__((address_space(3))) void*)l, 16, 0, 0);
}

// ---------------- x fp32 -> bf16 ----------------
__global__ void k_cvt_x(const float4* __restrict__ x, uint2* __restrict__ xb) {
  int i = blockIdx.x * 256 + threadIdx.x;     // grid sized exactly: 6291456/4 elems
  float4 v = x[i];
  uint2 o;
  o.x = pk2(v.x, v.y);
  o.y = pk2(v.z, v.w);
  xb[i] = o;
}

// ------------- W [K][N] fp32 -> Wt [N][K] bf16 -------------
__global__ __launch_bounds__(256) void k_wtrans(const float* __restrict__ w, u16* __restrict__ wt,
                                                int K, int N) {
  __shared__ float t[64][65];
  int n0 = blockIdx.x * 64, k0 = blockIdx.y * 64;
  int tid = threadIdx.x;
#pragma unroll
  for (int it = 0; it < 16; ++it) {
    int idx = it * 256 + tid;
    int r = idx >> 6, c = idx & 63;          // r = k-local, c = n-local
    t[r][c] = w[(size_t)(k0 + r) * N + n0 + c];
  }
  __syncthreads();
#pragma unroll
  for (int it = 0; it < 16; ++it) {
    int idx = it * 256 + tid;
    int r = idx >> 6, c = idx & 63;          // r = n-local, c = k-local
    wt[(size_t)(n0 + r) * K + k0 + c] = f2b(t[c][r]);
  }
}

// ------------- GEMM mainloop (m97-style): A[M][768] bf16 x Bt[N][768] bf16 -------------
#define GEMM_MAIN(A_, Bt_)                                                              \
  __shared__ u16 As[128 * 32];                                                          \
  __shared__ u16 Bs[128 * 32];                                                          \
  const int tid = threadIdx.x;                                                          \
  const int m0 = blockIdx.x * 128, n0 = blockIdx.y * 128;                               \
  const int wave = tid >> 6, lane = tid & 63, ln = lane & 15, lg = lane >> 4;           \
  const int wr = wave >> 1, wc = wave & 1;                                              \
  f32x4 acc[4][4] = {};                                                                 \
  const int f0 = tid, f1 = tid + 256;                                                   \
  const size_t ga0 = (size_t)(m0 + (f0 >> 2)) * 768 + (f0 & 3) * 8;                     \
  const size_t ga1 = (size_t)(m0 + (f1 >> 2)) * 768 + (f1 & 3) * 8;                     \
  const size_t gb0 = (size_t)(n0 + (f0 >> 2)) * 768 + (f0 & 3) * 8;                     \
  const size_t gb1 = (size_t)(n0 + (f1 >> 2)) * 768 + (f1 & 3) * 8;                     \
  for (int kt = 0; kt < 24; ++kt) {                                                     \
    __syncthreads();                                                                    \
    gload_lds16(A_ + ga0 + kt * 32, &As[f0 * 8]);                                       \
    gload_lds16(A_ + ga1 + kt * 32, &As[f1 * 8]);                                       \
    gload_lds16(Bt_ + gb0 + kt * 32, &Bs[f0 * 8]);                                      \
    gload_lds16(Bt_ + gb1 + kt * 32, &Bs[f1 * 8]);                                      \
    __syncthreads();                                                                    \
    bf16x8 a[4], b[4];                                                                  \
    _Pragma("unroll") for (int i = 0; i < 4; ++i)                                       \
        a[i] = *(const bf16x8*)&As[(wr * 64 + i * 16 + ln) * 32 + lg * 8];              \
    _Pragma("unroll") for (int j = 0; j < 4; ++j)                                       \
        b[j] = *(const bf16x8*)&Bs[(wc * 64 + j * 16 + ln) * 32 + lg * 8];              \
    _Pragma("unroll") for (int i = 0; i < 4; ++i)                                       \
        _Pragma("unroll") for (int j = 0; j < 4; ++j)                                   \
            acc[i][j] = mfma16(a[i], b[j], acc[i][j]);                                  \
  }

// qkv = x @ Wqkv + b; scatter into Q(*0.125)/K [bh][s][d] and V^T [bh][d][s], all bf16
__global__ __launch_bounds__(256) void k_gemm_qkv(const u16* __restrict__ A, const u16* __restrict__ Bt,
                                                  const float* __restrict__ bias,
                                                  u16* __restrict__ Qw, u16* __restrict__ Kw,
                                                  u16* __restrict__ Vt) {
  GEMM_MAIN(A, Bt)
#pragma unroll
  for (int j = 0; j < 4; ++j) {
    int n = n0 + wc * 64 + j * 16 + ln;      // uniform route per frag (16-block never straddles 64-aligned splits)
    float bn = bias[n];
    if (n >= 1536) {                         // V: write transposed [bh][d][s], 4 consecutive s packed
      int h = (n - 1536) >> 6, d = (n - 1536) & 63;
#pragma unroll
      for (int i = 0; i < 4; ++i) {
        int mb = m0 + wr * 64 + i * 16 + lg * 4;   // 4-aligned; never crosses batch (2048|4)
        int bb = mb >> 11, s = mb & 2047;
        uint2 w;
        w.x = pk2(acc[i][j][0] + bn, acc[i][j][1] + bn);
        w.y = pk2(acc[i][j][2] + bn, acc[i][j][3] + bn);
        *(uint2*)&Vt[((size_t)(bb * NH + h) * HD + d) * SEQ + s] = w;
      }
    } else {
      u16* dst; int nn; float scale;
      if (n < 768) { dst = Qw; nn = n;       scale = 0.125f; }
      else         { dst = Kw; nn = n - 768; scale = 1.0f;  }
      int h = nn >> 6, d = nn & 63;
#pragma unroll
      for (int i = 0; i < 4; ++i) {
        int mb = m0 + wr * 64 + i * 16 + lg * 4;
#pragma unroll
        for (int r = 0; r < 4; ++r) {
          int m = mb + r;
          int bb = m >> 11, s = m & 2047;
          float v = (acc[i][j][r] + bn) * scale;
          dst[((size_t)(bb * NH + h) * SEQ + s) * HD + d] = f2b(v);
        }
      }
    }
  }
}

// out = attn_bf @ Wo + bo  (fp32 out)
__global__ __launch_bounds__(256) void k_gemm_out(const u16* __restrict__ A, const u16* __restrict__ Bt,
                                                  const float* __restrict__ bias, float* __restrict__ C) {
  GEMM_MAIN(A, Bt)
#pragma unroll
  for (int j = 0; j < 4; ++j) {
    int n = n0 + wc * 64 + j * 16 + ln;
    float bn = bias[n];
#pragma unroll
    for (int i = 0; i < 4; ++i) {
      int mb = m0 + wr * 64 + i * 16 + lg * 4;
#pragma unroll
      for (int r = 0; r < 4; ++r) {
        C[(size_t)(mb + r) * 768 + n] = acc[i][j][r] + bn;
      }
    }
  }
}

// ------------- flash attention: Q[bh][s][d], K[bh][s][d], Vt[bh][d][s] -> Ob[b*S][E] bf16 -------------
__global__ __launch_bounds__(256) void k_attn(const u16* __restrict__ Qw, const u16* __restrict__ Kw,
                                              const u16* __restrict__ Vt, u16* __restrict__ Ob) {
  __shared__ __align__(16) u16 P[4][32 * 72];   // per-wave P buffer: no __syncthreads in this kernel
  const int bh = blockIdx.y;
  const int q0 = blockIdx.x * 128;
  const int wave = threadIdx.x >> 6, lane = threadIdx.x & 63, ln = lane & 15, lg = lane >> 4;
  const u16* Qb = Qw + ((size_t)bh * SEQ + q0 + wave * 32) * HD;
  const u16* Kb = Kw + (size_t)bh * SEQ * HD;
  const u16* Vb = Vt + (size_t)bh * HD * SEQ;
  u16* Pw = P[wave];

  bf16x8 qf[2][2];
#pragma unroll
  for (int qi = 0; qi < 2; ++qi)
#pragma unroll
    for (int kk = 0; kk < 2; ++kk)
      qf[qi][kk] = *(const bf16x8*)&Qb[(qi * 16 + ln) * HD + kk * 32 + lg * 8];

  f32x4 o[2][4] = {};
  float m_r[2] = {-1e30f, -1e30f}, l_r[2] = {0.f, 0.f};

  for (int t0 = 0; t0 < SEQ; t0 += 64) {
    // S^T = K * Q  (swapped: softmax stats land on lane&15)
    f32x4 st[4][2];
#pragma unroll
    for (int tf = 0; tf < 4; ++tf) {
      bf16x8 k0 = *(const bf16x8*)&Kb[(size_t)(t0 + tf * 16 + ln) * HD + lg * 8];
      bf16x8 k1 = *(const bf16x8*)&Kb[(size_t)(t0 + tf * 16 + ln) * HD + 32 + lg * 8];
#pragma unroll
      for (int qi = 0; qi < 2; ++qi) {
        f32x4 z = {0.f, 0.f, 0.f, 0.f};
        z = mfma16(k0, qf[qi][0], z);
        z = mfma16(k1, qf[qi][1], z);
        st[tf][qi] = z;
      }
    }
    // online softmax (per q-column = lane&15)
    float mnew[2], corr[2];
#pragma unroll
    for (int qi = 0; qi < 2; ++qi) {
      float mx = st[0][qi][0];
#pragma unroll
      for (int tf = 0; tf < 4; ++tf)
#pragma unroll
        for (int r = 0; r < 4; ++r) mx = fmaxf(mx, st[tf][qi][r]);
      mx = fmaxf(mx, __shfl_xor(mx, 16));
      mx = fmaxf(mx, __shfl_xor(mx, 32));
      float mn = fmaxf(m_r[qi], mx);
      mnew[qi] = mn;
      corr[qi] = __expf(m_r[qi] - mn);
      m_r[qi] = mn;
    }
    float lp[2] = {0.f, 0.f};
#pragma unroll
    for (int tf = 0; tf < 4; ++tf)
#pragma unroll
      for (int qi = 0; qi < 2; ++qi)
#pragma unroll
        for (int r = 0; r < 4; ++r) {
          float p = __expf(st[tf][qi][r] - mnew[qi]);
          st[tf][qi][r] = p;
          lp[qi] += p;
        }
#pragma unroll
    for (int qi = 0; qi < 2; ++qi) {
      lp[qi] += __shfl_xor(lp[qi], 16);
      lp[qi] += __shfl_xor(lp[qi], 32);
      l_r[qi] = l_r[qi] * corr[qi] + lp[qi];
    }
    // P^T frag (col q, rows t contiguous per reg) -> P_lds[q][t] as packed b64 writes
#pragma unroll
    for (int qi = 0; qi < 2; ++qi)
#pragma unroll
      for (int tf = 0; tf < 4; ++tf) {
        uint2 w;
        w.x = pk2(st[tf][qi][0], st[tf][qi][1]);
        w.y = pk2(st[tf][qi][2], st[tf][qi][3]);
        *(uint2*)&Pw[(qi * 16 + ln) * 72 + tf * 16 + lg * 4] = w;
      }
    asm volatile("s_waitcnt lgkmcnt(0)" ::: "memory");
    __builtin_amdgcn_sched_barrier(0);
    // rescale O (corr lives on lane&15=q; O rows are (lg*4+r))
    float cr[2][4];
#pragma unroll
    for (int qi = 0; qi < 2; ++qi)
#pragma unroll
      for (int r = 0; r < 4; ++r) cr[qi][r] = __shfl(corr[qi], lg * 4 + r, 16);
#pragma unroll
    for (int qi = 0; qi < 2; ++qi)
#pragma unroll
      for (int df = 0; df < 4; ++df)
#pragma unroll
        for (int r = 0; r < 4; ++r) o[qi][df][r] *= cr[qi][r];
    // O += P @ V   (A = P[q][t] from LDS, B = Vt[d][t] from global, both k=t contiguous)
#pragma unroll
    for (int tk = 0; tk < 2; ++tk) {
      bf16x8 pa0 = *(const bf16x8*)&Pw[(0 * 16 + ln) * 72 + tk * 32 + lg * 8];
      bf16x8 pa1 = *(const bf16x8*)&Pw[(1 * 16 + ln) * 72 + tk * 32 + lg * 8];
#pragma unroll
      for (int df = 0; df < 4; ++df) {
        bf16x8 bv = *(const bf16x8*)&Vb[(size_t)(df * 16 + ln) * SEQ + t0 + tk * 32 + lg * 8];
        o[0][df] = mfma16(pa0, bv, o[0][df]);
        o[1][df] = mfma16(pa1, bv, o[1][df]);
      }
    }
  }
  // epilogue: O /= l, write [b*S][E] bf16
  const int h = bh % NH, b = bh / NH;
#pragma unroll
  for (int qi = 0; qi < 2; ++qi) {
    float li[4];
#pragma unroll
    for (int r = 0; r < 4; ++r) {
      float lv = __shfl(l_r[qi], lg * 4 + r, 16);
      li[r] = 1.0f / lv;
    }
#pragma unroll
    for (int df = 0; df < 4; ++df) {
      int ecol = h * HD + df * 16 + ln;
#pragma unroll
      for (int r = 0; r < 4; ++r) {
        int s = q0 + wave * 32 + qi * 16 + lg * 4 + r;
        Ob[((size_t)(b * SEQ + s)) * E_DIM + ecol] = f2b(o[qi][df][r] * li[r]);
      }
    }
  }
}

extern "C" void kernel_launch(void* const* d_in, const int* in_sizes, int n_in,
                              void* d_out, int out_size, void* d_ws, size_t ws_size,
                              hipStream_t stream) {
  const float* x    = (const float*)d_in[0];
  const float* Wqkv = (const float*)d_in[1];
  const float* bqkv = (const float*)d_in[2];
  const float* Wo   = (const float*)d_in[3];
  const float* bo   = (const float*)d_in[4];
  float* out = (float*)d_out;

  // ws needs only 29,884,416 B (~28.5 MiB). Q/K live in d_out (exactly out_size*4
  // = 25,165,824 B = 2 x 12,582,912 B) until k_gemm_out overwrites it last.
  // Ab aliases xb (xb fully consumed by k_gemm_qkv before k_attn writes Ab).
  char* ws = (char*)d_ws;
  u16* xb    = (u16*)(ws);                // [8192][768] bf16   12,582,912 B  (also Ab)
  u16* wqkvt = (u16*)(ws + 12582912);     // [2304][768]         3,538,944 B
  u16* wot   = (u16*)(ws + 16121856);     // [768][768]          1,179,648 B
  u16* Vtw   = (u16*)(ws + 17301504);     // [48][64][2048]     12,582,912 B
  u16* Ab    = xb;
  u16* Qw    = (u16*)d_out;               // [48][2048][64]     12,582,912 B
  u16* Kw    = (u16*)d_out + 6291456;     // [48][2048][64]     12,582,912 B

  k_cvt_x<<<dim3(6144), dim3(256), 0, stream>>>((const float4*)x, (uint2*)xb);
  k_wtrans<<<dim3(36, 12), dim3(256), 0, stream>>>(Wqkv, wqkvt, 768, 2304);
  k_wtrans<<<dim3(12, 12), dim3(256), 0, stream>>>(Wo, wot, 768, 768);
  k_gemm_qkv<<<dim3(64, 18), dim3(256), 0, stream>>>(xb, wqkvt, bqkv, Qw, Kw, Vtw);
  k_attn<<<dim3(16, 48), dim3(256), 0, stream>>>(Qw, Kw, Vtw, Ab);
  k_gemm_out<<<dim3(64, 6), dim3(256), 0, stream>>>(Ab, wot, bo, out);
}